// Round 15
// baseline (267.502 us; speedup 1.0000x reference)
//
#include <hip/hip_runtime.h>
#include <math.h>

#define EPSF 1e-8f

typedef _Float16 f16x8 __attribute__((ext_vector_type(8)));
typedef float f32x4 __attribute__((ext_vector_type(4)));

#define GLOAD_LDS16(g, l)                                                      \
  __builtin_amdgcn_global_load_lds(                                            \
      (const __attribute__((address_space(1))) unsigned int*)(g),              \
      (__attribute__((address_space(3))) unsigned int*)(l), 16, 0, 0)

#define WAITV(n) asm volatile("s_waitcnt vmcnt(" #n ")" ::: "memory")
#define BAR() __builtin_amdgcn_s_barrier()

__device__ __forceinline__ unsigned int ord_from_float(float f) {
  unsigned int u = __float_as_uint(f);
  return (u & 0x80000000u) ? ~u : (u | 0x80000000u);
}

__device__ __forceinline__ float float_from_ord(unsigned int o) {
  return (o & 0x80000000u) ? __uint_as_float(o & 0x7fffffffu)
                           : __uint_as_float(~o);
}

__device__ __forceinline__ unsigned long long shfl_xor_u64(unsigned long long x, int m) {
  int lo = __shfl_xor((int)(unsigned int)(x & 0xffffffffull), m, 64);
  int hi = __shfl_xor((int)(unsigned int)(x >> 32), m, 64);
  return ((unsigned long long)(unsigned int)hi << 32) | (unsigned int)lo;
}

// ---------------- merged prep kernel ----------------
// A: Acat rows [hi(log)|hi(log)|lo(log)] (stride KPA), s_in, packed-init.
// B: Bcat rows [hi(tgt)|lo(tgt)|hi(tgt)], s_st.
__global__ __launch_bounds__(64) void prep_kernel(
    const float* __restrict__ inp, const float* __restrict__ tgt,
    _Float16* __restrict__ Acat, _Float16* __restrict__ Bcat,
    float* __restrict__ s_in, float* __restrict__ s_st,
    unsigned long long* __restrict__ packed,
    int N, int M, int Npad, int Mpad, int D, int DP, int KPA) {
  const int r = blockIdx.x;
  if (r < Npad) {
    _Float16* row = Acat + (size_t)r * KPA;
    float s = 0.f;
    for (int d = threadIdx.x; d < DP; d += 64) {
      float lg = 0.f;
      if (r < N && d < D) {
        float x = inp[(size_t)r * D + d];
        s += x;
        lg = logf(x + EPSF);
      }
      _Float16 h = (_Float16)lg;
      _Float16 l = (_Float16)(lg - (float)h);
      row[d] = h;
      row[DP + d] = h;
      row[2 * DP + d] = l;
    }
    for (int d = threadIdx.x; d < KPA - 3 * DP; d += 64)
      row[3 * DP + d] = (_Float16)0.f;
    #pragma unroll
    for (int m = 1; m < 64; m <<= 1) s += __shfl_xor(s, m, 64);
    if (threadIdx.x == 0 && r < N) {
      s_in[r] = s;
      packed[r] = ~0ull;
    }
  }
  if (r < Mpad) {
    _Float16* row = Bcat + (size_t)r * KPA;
    float s = 0.f;
    for (int d = threadIdx.x; d < DP; d += 64) {
      float x = 0.f;
      if (r < M && d < D) {
        x = tgt[(size_t)r * D + d];
        if (x > 1.0f)
          s += x * logf(x) - x + 0.5f * logf(6.283185307179586f * x);
      }
      _Float16 h = (_Float16)x;
      _Float16 l = (_Float16)(x - (float)h);
      row[d] = h;
      row[DP + d] = l;
      row[2 * DP + d] = h;
    }
    for (int d = threadIdx.x; d < KPA - 3 * DP; d += 64)
      row[3 * DP + d] = (_Float16)0.f;
    #pragma unroll
    for (int m = 1; m < 64; m <<= 1) s += __shfl_xor(s, m, 64);
    if (threadIdx.x == 0 && r < M) s_st[r] = s;
  }
}

// ---------------- MFMA pair-min kernel: 128x128, multi-block/CU ----------------
// 4 waves (2Mx2N), 64x64 per wave, BK=32, 2 LDS bufs (32 KB static ->
// 4-5 blocks/CU; low VGPR). Depth-1 prefetch + WAITV(0)+BAR per step; the
// per-step drain is hidden by co-resident blocks' independent barriers
// (cross-block TLP -- the m97 mechanism, 912 TF @128^2 with this discipline).
#define BT 128

__global__ __launch_bounds__(256) void mfma_pair_min_kernel(
    const _Float16* __restrict__ Acat, const _Float16* __restrict__ Bcat,
    const float* __restrict__ s_st, unsigned long long* __restrict__ packed,
    int N, int M, int KPA, int gy) {
  __shared__ __align__(16) _Float16 Ash[2][BT * 32];  // 2 x 8 KB
  __shared__ __align__(16) _Float16 Bsh[2][BT * 32];  // 2 x 8 KB
  const int t = threadIdx.x;
  const int lane = t & 63;
  const int wid = t >> 6;   // 0..3
  const int wr = wid >> 1;  // 0..1 -> 64 output rows each
  const int wc = wid & 1;   // 0..1 -> 64 output cols each

  // Bijective XCD chunking (m204; grid NOT divisible by 8) + column-major
  // walk inside each chunk: consecutive blocks share the B panel (L2 reuse).
  const int nwg = gridDim.x;
  const int q = nwg >> 3, r8 = nwg & 7;
  const int xcd = blockIdx.x & 7;
  const int idx = blockIdx.x >> 3;
  const int wg = (xcd < r8 ? xcd * (q + 1) : r8 * (q + 1) + (xcd - r8) * q) + idx;
  const int brow = wg % gy;
  const int bcol = wg / gy;
  const int row0 = brow * BT;
  const int col0 = bcol * BT;

  f32x4 acc[4][4] = {};

  // Staging (verified swizzle): wave wid owns rows [wid*32, wid*32+32) of A
  // and B per step; 2 gload_lds per operand (16 rows x 64B each). LDS dest
  // linear; global source slot pre-swizzled: LDS(r,s) = global(r, s^((r>>1)&3)).
  const int srow = lane >> 2;
  const int gs = (lane & 3) ^ ((lane >> 3) & 3);
  const _Float16* a0 = Acat + (size_t)(row0 + wid * 32 + srow) * KPA + gs * 8;
  const _Float16* a1 = a0 + (size_t)16 * KPA;
  const _Float16* b0 = Bcat + (size_t)(col0 + wid * 32 + srow) * KPA + gs * 8;
  const _Float16* b1 = b0 + (size_t)16 * KPA;

#define STAGE(buf_)                                                            \
  do {                                                                         \
    GLOAD_LDS16(a0, &Ash[buf_][wid * 1024]);                                   \
    GLOAD_LDS16(a1, &Ash[buf_][wid * 1024 + 512]);                             \
    GLOAD_LDS16(b0, &Bsh[buf_][wid * 1024]);                                   \
    GLOAD_LDS16(b1, &Bsh[buf_][wid * 1024 + 512]);                             \
  } while (0)

#define ADV() do { a0 += 32; a1 += 32; b0 += 32; b1 += 32; } while (0)

  const int rl = lane & 15;
  const int qq = lane >> 4;
  const int sa = qq ^ ((rl >> 1) & 3);  // swizzled k-slot

#define COMPUTE(buf_)                                                          \
  do {                                                                         \
    f16x8 af[4], bf[4];                                                        \
    _Pragma("unroll")                                                          \
    for (int m = 0; m < 4; ++m)                                                \
      af[m] = *(const f16x8*)(&Ash[buf_][(wr * 64 + m * 16 + rl) * 32 + sa * 8]); \
    _Pragma("unroll")                                                          \
    for (int n = 0; n < 4; ++n)                                                \
      bf[n] = *(const f16x8*)(&Bsh[buf_][(wc * 64 + n * 16 + rl) * 32 + sa * 8]); \
    __builtin_amdgcn_s_setprio(1);                                             \
    _Pragma("unroll")                                                          \
    for (int m = 0; m < 4; ++m)                                                \
      _Pragma("unroll")                                                        \
      for (int n = 0; n < 4; ++n)                                              \
        acc[m][n] = __builtin_amdgcn_mfma_f32_16x16x32_f16(af[m], bf[n],       \
                                                           acc[m][n], 0, 0, 0); \
    __builtin_amdgcn_s_setprio(0);                                             \
  } while (0)

  const int NT = KPA >> 5;  // 18 for D=180

  STAGE(0);
  WAITV(0);
  BAR();
  for (int kt = 0; kt < NT - 1; ++kt) {
    ADV();
    STAGE((kt + 1) & 1);  // issue next-step loads first; MFMA covers latency
    COMPUTE(kt & 1);
    WAITV(0);             // own stage landed; co-resident blocks hide drain
    BAR();
  }
  COMPUTE((NT - 1) & 1);

#undef STAGE
#undef ADV
#undef COMPUTE

  // ---- fused min/argmin epilogue (atomicMin, verified r3-r11) ----
  // C/D frag: col = lane&15, row = (lane>>4)*4 + reg   [guide §3, m89-verified]
  float stv[4];
  #pragma unroll
  for (int n = 0; n < 4; ++n) {
    int gj = col0 + wc * 64 + n * 16 + rl;
    stv[n] = (gj < M) ? s_st[gj] : __builtin_inff();
  }
  #pragma unroll
  for (int m = 0; m < 4; ++m) {
    #pragma unroll
    for (int g = 0; g < 4; ++g) {
      int grow = row0 + wr * 64 + m * 16 + qq * 4 + g;
      unsigned long long bst = ~0ull;
      #pragma unroll
      for (int n = 0; n < 4; ++n) {
        int gj = col0 + wc * 64 + n * 16 + rl;
        float val = stv[n] - acc[m][n][g];
        unsigned long long p =
            ((unsigned long long)ord_from_float(val) << 32) | (unsigned int)gj;
        if (p < bst) bst = p;
      }
      #pragma unroll
      for (int mm = 1; mm < 16; mm <<= 1) {
        unsigned long long o = shfl_xor_u64(bst, mm);
        if (o < bst) bst = o;
      }
      if (rl == 0 && grow < N) atomicMin(&packed[grow], bst);
    }
  }
}

// ---------------- reduce + final ----------------
__global__ __launch_bounds__(256) void reduce_kernel(
    const unsigned long long* __restrict__ packed,
    const float* __restrict__ s_in, float* __restrict__ out,
    unsigned long long* __restrict__ sumbuf, int N) {
  int i = blockIdx.x * 256 + threadIdx.x;
  double local = 0.0;
  if (i < N) {
    unsigned long long p = packed[i];
    out[1 + i] = (float)(unsigned int)(p & 0xffffffffull);
    float val = float_from_ord((unsigned int)(p >> 32));
    local = (double)(s_in[i] + val);
  }
  __shared__ double sh[256];
  sh[threadIdx.x] = local;
  __syncthreads();
  for (int o = 128; o > 0; o >>= 1) {
    if (threadIdx.x < o) sh[threadIdx.x] += sh[threadIdx.x + o];
    __syncthreads();
  }
  if (threadIdx.x == 0) {
    long long qv = __double2ll_rn(sh[0] * 1048576.0);  // fixed-point: deterministic
    atomicAdd(sumbuf, (unsigned long long)qv);
  }
}

__global__ void final_kernel(const unsigned long long* __restrict__ sumbuf,
                             float* __restrict__ out, int N) {
  if (threadIdx.x == 0)
    out[0] = (float)(((double)(long long)sumbuf[0] / 1048576.0) / (double)N);
}

extern "C" void kernel_launch(void* const* d_in, const int* in_sizes, int n_in,
                              void* d_out, int out_size, void* d_ws, size_t ws_size,
                              hipStream_t stream) {
  const float* inp = (const float*)d_in[0];
  const float* tgt = (const float*)d_in[1];
  float* out = (float*)d_out;

  int N = out_size - 1;  // outputs: [loss scalar, match[N]]
  int D = in_sizes[0] / N;
  int M = in_sizes[1] / D;

  int Npad = ((N + BT - 1) / BT) * BT;
  int Mpad = ((M + BT - 1) / BT) * BT;
  int DP = ((D + 31) / 32) * 32;
  int KPA = ((3 * DP + 31) / 32) * 32;  // 576 for D=180 -> 18 k-steps
  int gx = Mpad / BT, gy = Npad / BT;

  char* ws = (char*)d_ws;
  size_t off = 0;
  float* s_in = (float*)(ws + off); off += (size_t)N * 4;
  float* s_st = (float*)(ws + off); off += (size_t)M * 4;
  off = (off + 15) & ~(size_t)15;
  unsigned long long* sumbuf = (unsigned long long*)(ws + off); off += 16;
  unsigned long long* packed = (unsigned long long*)(ws + off); off += (size_t)N * 8;
  off = (off + 15) & ~(size_t)15;
  _Float16* Acat = (_Float16*)(ws + off); off += (size_t)Npad * KPA * 2;
  _Float16* Bcat = (_Float16*)(ws + off); off += (size_t)Mpad * KPA * 2;

  hipMemsetAsync(sumbuf, 0, 8, stream);

  int pgrid = Npad > Mpad ? Npad : Mpad;
  prep_kernel<<<pgrid, 64, 0, stream>>>(inp, tgt, Acat, Bcat, s_in, s_st,
                                        packed, N, M, Npad, Mpad, D, DP, KPA);

  mfma_pair_min_kernel<<<gx * gy, 256, 0, stream>>>(Acat, Bcat, s_st, packed,
                                                    N, M, KPA, gy);

  reduce_kernel<<<(N + 255) / 256, 256, 0, stream>>>(packed, s_in, out,
                                                     sumbuf, N);
  final_kernel<<<1, 64, 0, stream>>>(sumbuf, out, N);
}

// Round 16
// 207.881 us; speedup vs baseline: 1.2868x; 1.2868x over previous
//
#include <hip/hip_runtime.h>
#include <math.h>

#define EPSF 1e-8f

typedef _Float16 f16x8 __attribute__((ext_vector_type(8)));
typedef float f32x4 __attribute__((ext_vector_type(4)));

#define GLOAD_LDS16(g, l)                                                      \
  __builtin_amdgcn_global_load_lds(                                            \
      (const __attribute__((address_space(1))) unsigned int*)(g),              \
      (__attribute__((address_space(3))) unsigned int*)(l), 16, 0, 0)

#define WAITV(n) asm volatile("s_waitcnt vmcnt(" #n ")" ::: "memory")
#define BAR() __builtin_amdgcn_s_barrier()

__device__ __forceinline__ unsigned int ord_from_float(float f) {
  unsigned int u = __float_as_uint(f);
  return (u & 0x80000000u) ? ~u : (u | 0x80000000u);
}

__device__ __forceinline__ float float_from_ord(unsigned int o) {
  return (o & 0x80000000u) ? __uint_as_float(o & 0x7fffffffu)
                           : __uint_as_float(~o);
}

__device__ __forceinline__ unsigned long long shfl_xor_u64(unsigned long long x, int m) {
  int lo = __shfl_xor((int)(unsigned int)(x & 0xffffffffull), m, 64);
  int hi = __shfl_xor((int)(unsigned int)(x >> 32), m, 64);
  return ((unsigned long long)(unsigned int)hi << 32) | (unsigned int)lo;
}

// ---------------- merged prep kernel (vectorized) ----------------
// Segments contiguous at stride D (no per-segment padding):
//   Acat row: [hi(log) @0 | hi(log) @D | lo(log) @2D | zeros @3D..KPA)
//   Bcat row: [hi(tgt) @0 | lo(tgt) @D | hi(tgt) @2D | zeros]
// Also: s_in (row sums), s_st (Stirling sums), packed init.
__global__ __launch_bounds__(64) void prep_kernel(
    const float* __restrict__ inp, const float* __restrict__ tgt,
    _Float16* __restrict__ Acat, _Float16* __restrict__ Bcat,
    float* __restrict__ s_in, float* __restrict__ s_st,
    unsigned long long* __restrict__ packed,
    int N, int M, int Npad, int Mpad, int D, int KPA) {
  const int r = blockIdx.x;
  const int tid = threadIdx.x;
  const int NC4 = D >> 2;  // exact float4 chunks (D=180 -> 45)
  float sa = 0.f, sb = 0.f;

  _Float16* const arow = (r < Npad) ? Acat + (size_t)r * KPA : nullptr;
  _Float16* const brow = (r < Mpad) ? Bcat + (size_t)r * KPA : nullptr;
  const float4* const ain = (const float4*)(inp + (size_t)r * D);
  const float4* const bin = (const float4*)(tgt + (size_t)r * D);

  for (int c = tid; c < NC4; c += 64) {
    // ---- A ----
    if (arow) {
      float4 v = (r < N) ? ain[c] : make_float4(0.f, 0.f, 0.f, 0.f);
      float xs[4] = {v.x, v.y, v.z, v.w};
      #pragma unroll
      for (int e = 0; e < 4; ++e) {
        float x = xs[e];
        sa += x;
        float lg = (r < N) ? logf(x + EPSF) : 0.f;
        _Float16 h = (_Float16)lg;
        _Float16 l = (_Float16)(lg - (float)h);
        int d = c * 4 + e;
        arow[d] = h;
        arow[D + d] = h;
        arow[2 * D + d] = l;
      }
    }
    // ---- B ----
    if (brow) {
      float4 v = (r < M) ? bin[c] : make_float4(0.f, 0.f, 0.f, 0.f);
      float xs[4] = {v.x, v.y, v.z, v.w};
      #pragma unroll
      for (int e = 0; e < 4; ++e) {
        float x = xs[e];
        if (x > 1.0f)
          sb += x * logf(x) - x + 0.5f * logf(6.283185307179586f * x);
        _Float16 h = (_Float16)x;
        _Float16 l = (_Float16)(x - (float)h);
        int d = c * 4 + e;
        brow[d] = h;
        brow[D + d] = l;
        brow[2 * D + d] = h;
      }
    }
  }
  // scalar remainder (D % 4 != 0; none for D=180)
  for (int d = (NC4 << 2) + tid; d < D; d += 64) {
    if (arow) {
      float x = (r < N) ? inp[(size_t)r * D + d] : 0.f;
      sa += x;
      float lg = (r < N) ? logf(x + EPSF) : 0.f;
      _Float16 h = (_Float16)lg;
      _Float16 l = (_Float16)(lg - (float)h);
      arow[d] = h; arow[D + d] = h; arow[2 * D + d] = l;
    }
    if (brow) {
      float x = (r < M) ? tgt[(size_t)r * D + d] : 0.f;
      if (x > 1.0f)
        sb += x * logf(x) - x + 0.5f * logf(6.283185307179586f * x);
      _Float16 h = (_Float16)x;
      _Float16 l = (_Float16)(x - (float)h);
      brow[d] = h; brow[D + d] = l; brow[2 * D + d] = h;
    }
  }
  // zero pad [3D, KPA)  (KPA - 3D < 64)
  if (tid < KPA - 3 * D) {
    if (arow) arow[3 * D + tid] = (_Float16)0.f;
    if (brow) brow[3 * D + tid] = (_Float16)0.f;
  }

  #pragma unroll
  for (int m = 1; m < 64; m <<= 1) {
    sa += __shfl_xor(sa, m, 64);
    sb += __shfl_xor(sb, m, 64);
  }
  if (tid == 0) {
    if (r < N) { s_in[r] = sa; packed[r] = ~0ull; }
    if (r < M) s_st[r] = sb;
  }
}

// ---------------- MFMA pair-min kernel (r9 core — fastest verified) ----------------
// 256x256 tile, 8 waves (2Mx4N), BK=32, 2 LDS buffers (64 KiB dynamic).
// Per step: STAGE(t+1, other buf) -> COMPUTE(t) -> WAITV(0) -> BAR.
#define BT 256
#define UNITH 8192  // halves per (buf,op) unit: 256 rows x 32 halves = 16 KB

__global__ __launch_bounds__(512, 2) void mfma_pair_min_kernel(
    const _Float16* __restrict__ Acat, const _Float16* __restrict__ Bcat,
    const float* __restrict__ s_st, unsigned long long* __restrict__ packed,
    int N, int M, int KPA, int gx) {
  extern __shared__ __align__(16) _Float16 smem[];  // 4 * UNITH = 64 KiB
  const int t = threadIdx.x;
  const int lane = t & 63;
  const int wid = t >> 6;   // 0..7
  const int wr = wid >> 2;  // 0..1 -> 128 output rows
  const int wc = wid & 3;   // 0..3 -> 64 output cols

  // XCD chunking + column-major traversal inside each chunk (round-6 verified)
  const int nwg = gridDim.x;
  const int q8 = nwg >> 3;
  const int xcd = blockIdx.x & 7;
  const int i8 = blockIdx.x >> 3;
  int brow, bcol;
  if (q8 % gx == 0) {
    int bh = q8 / gx;
    brow = xcd * bh + i8 % bh;
    bcol = i8 / bh;
  } else {
    int wg = xcd * q8 + i8;
    brow = wg / gx;
    bcol = wg % gx;
  }
  const int row0 = brow * BT;
  const int col0 = bcol * BT;

  f32x4 acc[8][4] = {};

  // Staging (round-3/4 verified swizzle): LDS dest linear; global source slot
  // pre-swizzled: LDS(r,s) = global(r, s^((r>>1)&3)). 0 bank conflicts.
  const int srow = lane >> 2;
  const int gs = (lane & 3) ^ ((lane >> 3) & 3);
  const _Float16* a0 = Acat + (size_t)(row0 + wid * 32 + srow) * KPA + gs * 8;
  const _Float16* a1 = a0 + (size_t)16 * KPA;
  const _Float16* b0 = Bcat + (size_t)(col0 + wid * 32 + srow) * KPA + gs * 8;
  const _Float16* b1 = b0 + (size_t)16 * KPA;

#define STAGE(buf_)                                                            \
  do {                                                                         \
    _Float16* dA_ = smem + (buf_) * 2 * UNITH + wid * 1024;                    \
    _Float16* dB_ = dA_ + UNITH;                                               \
    GLOAD_LDS16(a0, dA_);                                                      \
    GLOAD_LDS16(a1, dA_ + 512);                                                \
    GLOAD_LDS16(b0, dB_);                                                      \
    GLOAD_LDS16(b1, dB_ + 512);                                                \
  } while (0)

#define ADV() do { a0 += 32; a1 += 32; b0 += 32; b1 += 32; } while (0)

  const int rl = lane & 15;
  const int qq = lane >> 4;
  const int sa = qq ^ ((rl >> 1) & 3);  // swizzled k-slot

#define COMPUTE(buf_)                                                          \
  do {                                                                         \
    const _Float16* pA_ = smem + (buf_) * 2 * UNITH;                           \
    const _Float16* pB_ = pA_ + UNITH;                                         \
    f16x8 af[8], bf[4];                                                        \
    _Pragma("unroll")                                                          \
    for (int m = 0; m < 8; ++m)                                                \
      af[m] = *(const f16x8*)(pA_ + (wr * 128 + m * 16 + rl) * 32 + sa * 8);   \
    _Pragma("unroll")                                                          \
    for (int n = 0; n < 4; ++n)                                                \
      bf[n] = *(const f16x8*)(pB_ + (wc * 64 + n * 16 + rl) * 32 + sa * 8);    \
    __builtin_amdgcn_s_setprio(1);                                             \
    _Pragma("unroll")                                                          \
    for (int m = 0; m < 8; ++m)                                                \
      _Pragma("unroll")                                                        \
      for (int n = 0; n < 4; ++n)                                              \
        acc[m][n] = __builtin_amdgcn_mfma_f32_16x16x32_f16(af[m], bf[n],       \
                                                           acc[m][n], 0, 0, 0); \
    __builtin_amdgcn_s_setprio(0);                                             \
  } while (0)

  const int NT = KPA >> 5;  // 17 for D=180 (KPA=544)

  STAGE(0);
  WAITV(0);
  BAR();
  for (int kt = 0; kt < NT - 1; ++kt) {
    ADV();
    STAGE((kt + 1) & 1);  // issue next-step loads first (MFMA covers latency)
    COMPUTE(kt & 1);
    WAITV(0);             // own 4 loads landed; BAR syncs all waves' stages
    BAR();
  }
  COMPUTE((NT - 1) & 1);

#undef STAGE
#undef ADV
#undef COMPUTE

  // ---- fused min/argmin epilogue (atomicMin, verified) ----
  // C/D frag: col = lane&15, row = (lane>>4)*4 + reg   [guide §3, m89-verified]
  float stv[4];
  #pragma unroll
  for (int n = 0; n < 4; ++n) {
    int gj = col0 + wc * 64 + n * 16 + rl;
    stv[n] = (gj < M) ? s_st[gj] : __builtin_inff();
  }
  #pragma unroll
  for (int m = 0; m < 8; ++m) {
    #pragma unroll
    for (int g = 0; g < 4; ++g) {
      int grow = row0 + wr * 128 + m * 16 + qq * 4 + g;
      unsigned long long bst = ~0ull;
      #pragma unroll
      for (int n = 0; n < 4; ++n) {
        int gj = col0 + wc * 64 + n * 16 + rl;
        float val = stv[n] - acc[m][n][g];
        unsigned long long p =
            ((unsigned long long)ord_from_float(val) << 32) | (unsigned int)gj;
        if (p < bst) bst = p;
      }
      #pragma unroll
      for (int mm = 1; mm < 16; mm <<= 1) {
        unsigned long long o = shfl_xor_u64(bst, mm);
        if (o < bst) bst = o;
      }
      if (rl == 0 && grow < N) atomicMin(&packed[grow], bst);
    }
  }
}

// ---------------- reduce + final ----------------
__global__ __launch_bounds__(256) void reduce_kernel(
    const unsigned long long* __restrict__ packed,
    const float* __restrict__ s_in, float* __restrict__ out,
    unsigned long long* __restrict__ sumbuf, int N) {
  int i = blockIdx.x * 256 + threadIdx.x;
  double local = 0.0;
  if (i < N) {
    unsigned long long p = packed[i];
    out[1 + i] = (float)(unsigned int)(p & 0xffffffffull);
    float val = float_from_ord((unsigned int)(p >> 32));
    local = (double)(s_in[i] + val);
  }
  __shared__ double sh[256];
  sh[threadIdx.x] = local;
  __syncthreads();
  for (int o = 128; o > 0; o >>= 1) {
    if (threadIdx.x < o) sh[threadIdx.x] += sh[threadIdx.x + o];
    __syncthreads();
  }
  if (threadIdx.x == 0) {
    long long q = __double2ll_rn(sh[0] * 1048576.0);  // fixed-point: deterministic
    atomicAdd(sumbuf, (unsigned long long)q);
  }
}

__global__ void final_kernel(const unsigned long long* __restrict__ sumbuf,
                             float* __restrict__ out, int N) {
  if (threadIdx.x == 0)
    out[0] = (float)(((double)(long long)sumbuf[0] / 1048576.0) / (double)N);
}

extern "C" void kernel_launch(void* const* d_in, const int* in_sizes, int n_in,
                              void* d_out, int out_size, void* d_ws, size_t ws_size,
                              hipStream_t stream) {
  const float* inp = (const float*)d_in[0];
  const float* tgt = (const float*)d_in[1];
  float* out = (float*)d_out;

  int N = out_size - 1;  // outputs: [loss scalar, match[N]]
  int D = in_sizes[0] / N;
  int M = in_sizes[1] / D;

  int Npad = ((N + BT - 1) / BT) * BT;
  int Mpad = ((M + BT - 1) / BT) * BT;
  int KPA = ((3 * D + 31) / 32) * 32;  // contiguous segments: 544 for D=180
  int gx = Mpad / BT, gy = Npad / BT;

  char* ws = (char*)d_ws;
  size_t off = 0;
  float* s_in = (float*)(ws + off); off += (size_t)N * 4;
  float* s_st = (float*)(ws + off); off += (size_t)M * 4;
  off = (off + 15) & ~(size_t)15;
  unsigned long long* sumbuf = (unsigned long long*)(ws + off); off += 16;
  unsigned long long* packed = (unsigned long long*)(ws + off); off += (size_t)N * 8;
  off = (off + 15) & ~(size_t)15;
  _Float16* Acat = (_Float16*)(ws + off); off += (size_t)Npad * KPA * 2;
  _Float16* Bcat = (_Float16*)(ws + off); off += (size_t)Mpad * KPA * 2;

  hipMemsetAsync(sumbuf, 0, 8, stream);

  int pgrid = Npad > Mpad ? Npad : Mpad;
  prep_kernel<<<pgrid, 64, 0, stream>>>(inp, tgt, Acat, Bcat, s_in, s_st,
                                        packed, N, M, Npad, Mpad, D, KPA);

  const int ldsBytes = 4 * UNITH * 2;  // 64 KiB
  hipFuncSetAttribute((const void*)mfma_pair_min_kernel,
                      hipFuncAttributeMaxDynamicSharedMemorySize, ldsBytes);
  mfma_pair_min_kernel<<<gx * gy, 512, ldsBytes, stream>>>(
      Acat, Bcat, s_st, packed, N, M, KPA, gx);

  reduce_kernel<<<(N + 255) / 256, 256, 0, stream>>>(packed, s_in, out,
                                                     sumbuf, N);
  final_kernel<<<1, 64, 0, stream>>>(sumbuf, out, N);
}